// Round 3
// baseline (544.684 us; speedup 1.0000x reference)
//
#include <hip/hip_runtime.h>
#include <stdint.h>

#define CA 64     // in channels
#define CB 128    // out channels
#define KOFF 27   // 3^3 offsets
#define BN_EPS 1e-4f

typedef short bf16x8 __attribute__((ext_vector_type(8)));
typedef float f32x4 __attribute__((ext_vector_type(4)));
typedef unsigned int u32x4 __attribute__((ext_vector_type(4)));
typedef unsigned short u16x4 __attribute__((ext_vector_type(4)));

__device__ __forceinline__ unsigned short f2bf(float f) {
  union { float f; uint32_t u; } c; c.f = f;
  uint32_t u = c.u;
  return (unsigned short)((u + 0x7FFFu + ((u >> 16) & 1u)) >> 16);  // RNE
}

// Barrier WITHOUT vmcnt drain: LDS visibility only. Safe: cross-wave data flows
// through LDS (ds_write -> lgkmcnt(0) -> s_barrier); in-flight global loads
// target VGPRs only and stay in flight (that's the pipeline).
__device__ __forceinline__ void barrier_lds() {
  asm volatile("s_waitcnt lgkmcnt(0)\n\ts_barrier" ::: "memory");
}

// ---- mask dtype detection: if int32 layout, bytes at i%4!=0 are all zero ----
__global__ void detect_mask_k(const unsigned char* __restrict__ m, int* flag) {
  unsigned v = 0;
  for (int i = threadIdx.x; i < 4096; i += 256)
    if (i & 3) v |= m[i];
  if (v) atomicOr(flag, 1);   // 1 => byte/bool layout, 0 => int32 layout
}

// ---- merged neighbor+mask: ne[i] = mask[i] ? nbr[i] : n (zero row) ----
__global__ void make_nbr_eff_k(const int* __restrict__ nbr, const void* __restrict__ mp,
                               const int* __restrict__ flag, int* __restrict__ ne, int n) {
  int i = blockIdx.x * blockDim.x + threadIdx.x;
  if (i >= n * KOFF) return;
  bool m = (*flag) ? (((const unsigned char*)mp)[i] != 0)
                   : (((const int*)mp)[i] != 0);
  ne[i] = m ? nbr[i] : n;
}

// ---- zero rows at index n of the bf16 feature buffers ----
__global__ void zero_rows_k(unsigned short* hb1, unsigned short* fb,
                            unsigned short* hb2, int n) {
  int i = threadIdx.x;
  if (i < CA) { hb1[(size_t)n * CA + i] = 0; fb[(size_t)n * CA + i] = 0; }
  if (i < CB) { hb2[(size_t)n * CB + i] = 0; }
}

// ---- all weight transposes + bf16 convert: wt[k][co][ci] = bf16(w[k][ci][co]) ----
__global__ void transpose_all_k(const float* __restrict__ W1, const float* __restrict__ W2,
                                const float* __restrict__ Wnin,
                                unsigned short* __restrict__ w1t, unsigned short* __restrict__ w2t,
                                unsigned short* __restrict__ wnt) {
  const int t1 = KOFF * CA * CB, t2 = KOFF * CB * CB, t3 = CA * CB;
  int idx = blockIdx.x * blockDim.x + threadIdx.x;
  if (idx < t1) {
    int ci = idx % CA; int r = idx / CA; int co = r % CB; int k = r / CB;
    w1t[idx] = f2bf(W1[((size_t)k * CA + ci) * CB + co]);
  } else if (idx < t1 + t2) {
    int j = idx - t1;
    int ci = j % CB; int r = j / CB; int co = r % CB; int k = r / CB;
    w2t[j] = f2bf(W2[((size_t)k * CB + ci) * CB + co]);
  } else if (idx < t1 + t2 + t3) {
    int j = idx - t1 - t2;
    int ci = j % CA; int co = j / CA;
    wnt[j] = f2bf(Wnin[(size_t)ci * CB + co]);
  }
}

// ---- per-channel sum & sumsq (training-mode BN stats) ----
template<int C>
__global__ void col_stats_k(const float* __restrict__ x, int n, float* __restrict__ sums) {
  __shared__ float ssum[C], ssq[C];
  int t = threadIdx.x;
  for (int i = t; i < C; i += 256) { ssum[i] = 0.f; ssq[i] = 0.f; }
  __syncthreads();
  const int c = t % C;
  const int rpb = 256 / C;
  float s = 0.f, q = 0.f;
  for (int r = blockIdx.x * rpb + t / C; r < n; r += gridDim.x * rpb) {
    float v = x[(size_t)r * C + c];
    s += v; q += v * v;
  }
  atomicAdd(&ssum[c], s);
  atomicAdd(&ssq[c], q);
  __syncthreads();
  for (int i = t; i < C; i += 256) {
    atomicAdd(&sums[i], ssum[i]);
    atomicAdd(&sums[C + i], ssq[i]);
  }
}

template<int C>
__global__ void bn_finalize_k(const float* __restrict__ sums, const float* __restrict__ gamma,
                              const float* __restrict__ beta, float* __restrict__ sc, int n) {
  int c = threadIdx.x;
  if (c >= C) return;
  float inv_n = 1.f / (float)n;
  float mean = sums[c] * inv_n;
  float var = sums[C + c] * inv_n - mean * mean;
  float rstd = rsqrtf(var + BN_EPS);
  float scale = gamma[c] * rstd;
  sc[c] = scale;
  sc[C + c] = beta[c] - mean * scale;
}

template<int C, bool RAW>
__global__ void bn_apply_k(const float* __restrict__ x, const float* __restrict__ sc,
                           unsigned short* __restrict__ h, unsigned short* __restrict__ raw,
                           int total) {
  int idx = (blockIdx.x * blockDim.x + threadIdx.x) * 4;
  if (idx >= total) return;
  f32x4 v = *(const f32x4*)&x[idx];
  int c0 = idx % C;
  u16x4 ho, ro;
#pragma unroll
  for (int j = 0; j < 4; j++) {
    float s = sc[c0 + j], b = sc[C + c0 + j];
    float hv = fmaxf(v[j] * s + b, 0.f);
    ho[j] = f2bf(hv);
    if (RAW) ro[j] = f2bf(v[j]);
  }
  *(u16x4*)&h[idx] = ho;
  if (RAW) *(u16x4*)&raw[idx] = ro;
}

// ---- deep-pipelined gather-GEMM subconv ----
// out[n,:] = sum_k hin[nbr_eff[n,k],:] @ W[k]   (+ FUSE: fb(rows) @ wnt)
// Block: 64 rows x 128 cols, 256 threads (4 waves of 64x32).
// Gather prefetch DEPTH 3 iterations (4-slot VGPR ring, ~12 loads in flight per
// wave) so the ~630-cyc L3 gather latency is covered; lgkm-only barrier keeps
// global loads in flight across iterations; masked rows resolved via zero-row
// index (nbr_eff), no mask tests in the hot loop.
template<int CIN, bool FUSE>
__launch_bounds__(256)
__global__ void conv_k(const unsigned short* __restrict__ hin,
                       const unsigned short* __restrict__ wt,
                       const int* __restrict__ nbr_eff,
                       const unsigned short* __restrict__ fbraw,
                       const unsigned short* __restrict__ wnt,
                       float* __restrict__ out, int n) {
  constexpr int TR = 64;
  constexpr int STR = CIN + 8;      // +16B pad: A-frag ds_reads land 2-way (free)
  constexpr int NKS = CIN / 32;     // MFMA K-steps per offset (2 or 4)
  constexpr int CH = CIN / 8;       // 16B chunks per row
  constexpr int NP = TR * CH / 256; // staging loads per thread per iteration

  __shared__ alignas(16) unsigned short tile[2][TR * STR];
  __shared__ int lnbr[TR * KOFF];

  const int t = threadIdx.x;
  const int rowbase = blockIdx.x * TR;
  const int nrows = min(TR, n - rowbase);

  // stage merged neighbor indices; out-of-range rows -> zero row n
  for (int i = t; i < TR * KOFF; i += 256) {
    int r = i / KOFF;
    lnbr[i] = (rowbase + r < n) ? nbr_eff[(size_t)rowbase * KOFF + i] : n;
  }
  __syncthreads();

  const int lane = t & 63;
  const int wave = t >> 6;
  const int l16 = lane & 15;
  const int quad = lane >> 4;
  const int colbase = wave * 32;
  const int goff = (t % CH) * 8;    // channel offset within row (shorts)
  const int grow = t / CH;          // row within a staging pass
  const int boff0 = (colbase + l16) * CIN + quad * 8;
  const int boff1 = boff0 + 16 * CIN;

  f32x4 acc[4][2];
#pragma unroll
  for (int i = 0; i < 4; i++) { acc[i][0] = f32x4{0,0,0,0}; acc[i][1] = f32x4{0,0,0,0}; }

  bf16x8 bfr[2][2 * NKS];
  u32x4 gr[4][NP];                  // 4-slot gather ring (depth-3 pipeline)

  // ---- prologue: issue g(0..3), b(0), b(1); NiN MFMA; commit g(0) ----
#pragma unroll
  for (int j = 0; j < 4; j++) {
#pragma unroll
    for (int p = 0; p < NP; p++) {
      int r = p * (256 / CH) + grow;
      int idx = lnbr[r * KOFF + j];
      gr[j][p] = *(const u32x4*)&hin[(size_t)idx * CIN + goff];
    }
  }
#pragma unroll
  for (int ks = 0; ks < NKS; ks++) {
    bfr[0][2 * ks]     = *(const bf16x8*)&wt[boff0 + ks * 32];
    bfr[0][2 * ks + 1] = *(const bf16x8*)&wt[boff1 + ks * 32];
    const unsigned short* wk = wt + (size_t)CB * CIN;
    bfr[1][2 * ks]     = *(const bf16x8*)&wk[boff0 + ks * 32];
    bfr[1][2 * ks + 1] = *(const bf16x8*)&wk[boff1 + ks * 32];
  }

  if constexpr (FUSE) {
    // NiN shortcut: acc += fb(rows) @ wnt, A-frags direct from global (coalesced)
#pragma unroll
    for (int ks = 0; ks < CA / 32; ks++) {
      bf16x8 b0 = *(const bf16x8*)&wnt[(colbase + l16) * CA + ks * 32 + quad * 8];
      bf16x8 b1 = *(const bf16x8*)&wnt[(colbase + 16 + l16) * CA + ks * 32 + quad * 8];
#pragma unroll
      for (int rt = 0; rt < 4; rt++) {
        int g = rowbase + rt * 16 + l16; g = (g < n) ? g : n;
        bf16x8 a = *(const bf16x8*)&fbraw[(size_t)g * CA + ks * 32 + quad * 8];
        acc[rt][0] = __builtin_amdgcn_mfma_f32_16x16x32_bf16(a, b0, acc[rt][0], 0, 0, 0);
        acc[rt][1] = __builtin_amdgcn_mfma_f32_16x16x32_bf16(a, b1, acc[rt][1], 0, 0, 0);
      }
    }
  }

#pragma unroll
  for (int p = 0; p < NP; p++) {    // commit g(0) -> tile[0]
    int r = p * (256 / CH) + grow;
    *(u32x4*)&tile[0][r * STR + goff] = gr[0][p];
  }
  barrier_lds();

  // ---- main loop (fully unrolled; ring indices fold to registers) ----
#pragma unroll
  for (int k = 0; k < KOFF; k++) {
    const int cur = k & 1;
#pragma unroll
    for (int ks = 0; ks < NKS; ks++) {
#pragma unroll
      for (int rt = 0; rt < 4; rt++) {
        bf16x8 a = *(const bf16x8*)&tile[cur][(rt * 16 + l16) * STR + ks * 32 + quad * 8];
        acc[rt][0] = __builtin_amdgcn_mfma_f32_16x16x32_bf16(a, bfr[cur][2 * ks],     acc[rt][0], 0, 0, 0);
        acc[rt][1] = __builtin_amdgcn_mfma_f32_16x16x32_bf16(a, bfr[cur][2 * ks + 1], acc[rt][1], 0, 0, 0);
      }
    }
    if (k + 4 < KOFF) {   // issue g(k+4) into slot k&3 (freed by write at iter k-1)
#pragma unroll
      for (int p = 0; p < NP; p++) {
        int r = p * (256 / CH) + grow;
        int idx = lnbr[r * KOFF + (k + 4)];
        gr[(k + 4) & 3][p] = *(const u32x4*)&hin[(size_t)idx * CIN + goff];
      }
    }
    if (k + 2 < KOFF) {   // b-frags for k+2 into regs just consumed
      const unsigned short* wk = wt + (size_t)(k + 2) * CB * CIN;
#pragma unroll
      for (int ks = 0; ks < NKS; ks++) {
        bfr[cur][2 * ks]     = *(const bf16x8*)&wk[boff0 + ks * 32];
        bfr[cur][2 * ks + 1] = *(const bf16x8*)&wk[boff1 + ks * 32];
      }
    }
    if (k + 1 < KOFF) {   // commit g(k+1): its loads are 3 iterations old
#pragma unroll
      for (int p = 0; p < NP; p++) {
        int r = p * (256 / CH) + grow;
        *(u32x4*)&tile[(k + 1) & 1][r * STR + goff] = gr[(k + 1) & 3][p];
      }
      barrier_lds();
    }
  }

  // epilogue: C/D layout col=lane&15, row=(lane>>4)*4+reg
#pragma unroll
  for (int rt = 0; rt < 4; rt++) {
#pragma unroll
    for (int ct = 0; ct < 2; ct++) {
#pragma unroll
      for (int i = 0; i < 4; i++) {
        int r = rt * 16 + quad * 4 + i;
        if (r < nrows) {
          int c = colbase + ct * 16 + l16;
          out[(size_t)(rowbase + r) * CB + c] = acc[rt][ct][i];
        }
      }
    }
  }
}

extern "C" void kernel_launch(void* const* d_in, const int* in_sizes, int n_in,
                              void* d_out, int out_size, void* d_ws, size_t ws_size,
                              hipStream_t stream) {
  const float* feat   = (const float*)d_in[0];
  const float* gamma1 = (const float*)d_in[1];
  const float* beta1  = (const float*)d_in[2];
  const float* W1     = (const float*)d_in[3];
  const float* gamma2 = (const float*)d_in[4];
  const float* beta2  = (const float*)d_in[5];
  const float* W2     = (const float*)d_in[6];
  const float* Wnin   = (const float*)d_in[7];
  const int*   nbr    = (const int*)d_in[8];
  const void*  mask   = d_in[9];
  float* out = (float*)d_out;

  const int n = in_sizes[0] / CA;  // 100000

  char* ws = (char*)d_ws;
  size_t off = 0;
  auto alloc = [&](size_t bytes) { size_t p = off; off += (bytes + 255) & ~(size_t)255; return p; };
  int*            flag  = (int*)           (ws + alloc(256));
  float*          sums1 = (float*)         (ws + alloc(2 * CA * 4));
  float*          sums2 = (float*)         (ws + alloc(2 * CB * 4));
  float*          sc1   = (float*)         (ws + alloc(2 * CA * 4));
  float*          sc2   = (float*)         (ws + alloc(2 * CB * 4));
  int*            neff  = (int*)           (ws + alloc((size_t)n * KOFF * 4));
  unsigned short* fb    = (unsigned short*)(ws + alloc((size_t)(n + 1) * CA * 2));
  unsigned short* hb1   = (unsigned short*)(ws + alloc((size_t)(n + 1) * CA * 2));
  float*          out1  = (float*)         (ws + alloc((size_t)n * CB * 4));
  unsigned short* hb2   = (unsigned short*)(ws + alloc((size_t)(n + 1) * CB * 2));
  unsigned short* w1t   = (unsigned short*)(ws + alloc((size_t)KOFF * CB * CA * 2));
  unsigned short* w2t   = (unsigned short*)(ws + alloc((size_t)KOFF * CB * CB * 2));
  unsigned short* wnt   = (unsigned short*)(ws + alloc((size_t)CB * CA * 2));

  // zero flag + stats accumulators (ws is poisoned 0xAA before every launch)
  hipMemsetAsync(d_ws, 0, 1792, stream);

  detect_mask_k<<<1, 256, 0, stream>>>((const unsigned char*)mask, flag);
  make_nbr_eff_k<<<(n * KOFF + 255) / 256, 256, 0, stream>>>(nbr, mask, flag, neff, n);
  zero_rows_k<<<1, 256, 0, stream>>>(hb1, fb, hb2, n);

  {
    int tot = KOFF * CA * CB + KOFF * CB * CB + CA * CB;
    transpose_all_k<<<(tot + 255) / 256, 256, 0, stream>>>(W1, W2, Wnin, w1t, w2t, wnt);
  }

  // stage 1: BN stats -> scale/shift -> h1 (bn+relu bf16) + raw feat bf16
  col_stats_k<CA><<<256, 256, 0, stream>>>(feat, n, sums1);
  bn_finalize_k<CA><<<1, CA, 0, stream>>>(sums1, gamma1, beta1, sc1, n);
  bn_apply_k<CA, true><<<(n * CA / 4 + 255) / 256, 256, 0, stream>>>(feat, sc1, hb1, fb, n * CA);

  // conv1: out1 = subconv(h1, W1)  [N,128] fp32
  conv_k<CA, false><<<(n + 63) / 64, 256, 0, stream>>>(hb1, w1t, neff, nullptr, nullptr, out1, n);

  // stage 2
  col_stats_k<CB><<<256, 256, 0, stream>>>(out1, n, sums2);
  bn_finalize_k<CB><<<1, CB, 0, stream>>>(sums2, gamma2, beta2, sc2, n);
  bn_apply_k<CB, false><<<(n * CB / 4 + 255) / 256, 256, 0, stream>>>(out1, sc2, hb2, nullptr, n * CB);

  // conv2 + fused NiN shortcut
  conv_k<CB, true><<<(n + 63) / 64, 256, 0, stream>>>(hb2, w2t, neff, fb, wnt, out, n);
}